// Round 6
// baseline (1204.847 us; speedup 1.0000x reference)
//
#include <hip/hip_runtime.h>
#include <cstdint>
#include <cstddef>

#define B_SZ   2
#define L_SZ   2048
#define BL     (B_SZ * L_SZ)   // 4096
#define DMODEL 512
#define DINNER 1024
#define DSTATE 16
#define DTRANK 32
#define PF     8               // scan prefetch depth (register ring, statically indexed)
#define DTROWS 16              // rows per block in dt_softplus_k (Wdt reuse factor)

typedef unsigned short u16;
typedef __attribute__((ext_vector_type(8))) short          bf16x8;  // 8 bf16 in 4 VGPRs (guide §3)
typedef __attribute__((ext_vector_type(8))) unsigned short u16x8;
typedef __attribute__((ext_vector_type(4))) float          f32x4;

// async global->LDS, 16B per lane, linear dest (wave-uniform base + lane*16)
__device__ __forceinline__ void gload16(const void* g, void* l) {
    __builtin_amdgcn_global_load_lds(
        (const __attribute__((address_space(1))) unsigned int*)g,
        (__attribute__((address_space(3))) unsigned int*)l, 16, 0, 0);
}

// ---------------- fp32 -> bf16 hi/lo split (hi = rne(x), lo = rne(x - hi)) ----------------
// 8 elems/thread. src is [rows][2^shift] contiguous; dst rows have stride dst_stride
// and column offset col_off (for building the [m | context] concat).
__global__ __launch_bounds__(256) void cvt_hl_k(
    const float* __restrict__ src, u16* __restrict__ hi, u16* __restrict__ lo,
    int shift, int dst_stride, int col_off)
{
    const long long base = ((long long)blockIdx.x * 256 + threadIdx.x) * 8;
    const long long row  = base >> shift;
    const int       col  = (int)(base & ((1 << shift) - 1));
    float4 f0 = *(const float4*)(src + base);
    float4 f1 = *(const float4*)(src + base + 4);
    float f[8] = {f0.x, f0.y, f0.z, f0.w, f1.x, f1.y, f1.z, f1.w};
    u16x8 h8, l8;
#pragma unroll
    for (int i = 0; i < 8; ++i) {
        unsigned u  = __float_as_uint(f[i]);
        unsigned hb = (u + 0x7fffu + ((u >> 16) & 1u)) >> 16;
        float    hf = __uint_as_float(hb << 16);
        float    lf = f[i] - hf;                       // exact in fp32 (EFT split)
        unsigned ul = __float_as_uint(lf);
        unsigned lb = (ul + 0x7fffu + ((ul >> 16) & 1u)) >> 16;
        h8[i] = (u16)hb; l8[i] = (u16)lb;
    }
    const long long d = row * dst_stride + col_off + col;
    *(u16x8*)(hi + d) = h8;
    *(u16x8*)(lo + d) = l8;
}

// ---------------- MFMA GEMM: C[M,N] = (Ah+Al)[M,K] @ (Wh+Wl)[N,K]^T (lo*lo dropped) ----
// m97 structure: BM=128, BN=NF*32, BK=32, 4 waves, single-buffered 2-barrier loop,
// global_load_lds width 16 with LINEAR LDS (no swizzle: T2 measured null at 2-phase).
// Frags: A lane row = lane&15, k = (lane>>4)*8+j ; B lane col = lane&15, same k
// (m92-verified B^T-input pattern). C/D: col = lane&15, row = (lane>>4)*4+reg (m89/m91).
// Staging: lane L of one gload16 covers group row L>>2, u16 cols (L&3)*8.. -> LDS byte
// L*16 of the 16-row group (linear-dest rule, m104).
// EPI: 0 = plain f32 store; 1 = C[o] = Mul[o] * sigmoid(acc + bias[col]).
template<int NF, int EPI>
__global__ __launch_bounds__(256) void gemm_bf16hl(
    const u16* __restrict__ Ah, const u16* __restrict__ Al,
    const u16* __restrict__ Wh, const u16* __restrict__ Wl,
    const float* __restrict__ bias, const float* __restrict__ Mul,
    float* __restrict__ C, int M, int N, int K)
{
    constexpr int BN  = NF * 32;
    constexpr int NIB = BN / 16;        // 16-row stage groups per B array
    constexpr int TOT = 16 + 2 * NIB;   // total stage issues (Ah:8, Al:8, Bh, Bl)
    __shared__ u16 sAh[128][32], sAl[128][32];
    __shared__ u16 sBh[BN][32],  sBl[BN][32];

    const int tid  = threadIdx.x;
    const int w    = tid >> 6;
    const int lane = tid & 63;
    const int bm   = blockIdx.x * 128;
    const int bn   = blockIdx.y * BN;
    const int wm   = w >> 1;            // wave row-group (0..1) -> 64 rows
    const int wn   = w & 1;             // wave col-group (0..1) -> NF*16 cols
    const int lm   = lane & 15;
    const int lk8  = (lane >> 4) * 8;   // k-offset of this lane's 8 bf16
    const int srow = lane >> 2;         // staging: row within 16-row group
    const int scol = (lane & 3) * 8;    // staging: k-offset (8 bf16 = 16B)

    f32x4 acc[4][NF];
#pragma unroll
    for (int i = 0; i < 4; ++i)
#pragma unroll
        for (int j = 0; j < NF; ++j) acc[i][j] = (f32x4){0.f, 0.f, 0.f, 0.f};

    for (int k0 = 0; k0 < K; k0 += 32) {
        __syncthreads();                                   // prev ds_reads done before overwrite
        for (int idx = w; idx < TOT; idx += 4) {           // wave-uniform decode
            const u16* gs; u16* ls;
            if (idx < 8)            { gs = Ah + (size_t)(bm + idx * 16 + srow) * K;              ls = &sAh[idx * 16][0]; }
            else if (idx < 16)      { gs = Al + (size_t)(bm + (idx - 8) * 16 + srow) * K;        ls = &sAl[(idx - 8) * 16][0]; }
            else if (idx < 16 + NIB){ gs = Wh + (size_t)(bn + (idx - 16) * 16 + srow) * K;       ls = &sBh[(idx - 16) * 16][0]; }
            else                    { gs = Wl + (size_t)(bn + (idx - 16 - NIB) * 16 + srow) * K; ls = &sBl[(idx - 16 - NIB) * 16][0]; }
            gload16(gs + k0 + scol, ls);
        }
        __syncthreads();                                   // compiler drains vmcnt(0) before barrier

        bf16x8 a_h[4], a_l[4], b_h[NF], b_l[NF];
#pragma unroll
        for (int mi = 0; mi < 4; ++mi) {
            a_h[mi] = *(const bf16x8*)&sAh[wm * 64 + mi * 16 + lm][lk8];
            a_l[mi] = *(const bf16x8*)&sAl[wm * 64 + mi * 16 + lm][lk8];
        }
#pragma unroll
        for (int ni = 0; ni < NF; ++ni) {
            b_h[ni] = *(const bf16x8*)&sBh[wn * (NF * 16) + ni * 16 + lm][lk8];
            b_l[ni] = *(const bf16x8*)&sBl[wn * (NF * 16) + ni * 16 + lm][lk8];
        }
#pragma unroll
        for (int mi = 0; mi < 4; ++mi)
#pragma unroll
            for (int ni = 0; ni < NF; ++ni) {
                acc[mi][ni] = __builtin_amdgcn_mfma_f32_16x16x32_bf16(a_h[mi], b_h[ni], acc[mi][ni], 0, 0, 0);
                acc[mi][ni] = __builtin_amdgcn_mfma_f32_16x16x32_bf16(a_h[mi], b_l[ni], acc[mi][ni], 0, 0, 0);
                acc[mi][ni] = __builtin_amdgcn_mfma_f32_16x16x32_bf16(a_l[mi], b_h[ni], acc[mi][ni], 0, 0, 0);
            }
    }

    const int lr4 = (lane >> 4) * 4;
#pragma unroll
    for (int mi = 0; mi < 4; ++mi)
#pragma unroll
        for (int ni = 0; ni < NF; ++ni)
#pragma unroll
            for (int r = 0; r < 4; ++r) {
                const int row = bm + wm * 64 + mi * 16 + lr4 + r;
                const int col = bn + wn * (NF * 16) + ni * 16 + lm;
                const size_t o = (size_t)row * N + col;
                if (EPI == 0) {
                    C[o] = acc[mi][ni][r];
                } else {
                    const float v = acc[mi][ni][r] + bias[col];
                    C[o] = Mul[o] / (1.f + expf(-v));
                }
            }
}

// ---------------- small vector GEMM for x_proj (N=64): C = A @ W^T ----------------
__global__ __launch_bounds__(256) void gemm_xproj(
    const float* __restrict__ A, const float* __restrict__ W,
    float* __restrict__ C, int M, int N, int K)
{
    __shared__ float As[16][64];
    __shared__ float Ws[16][64];
    const int tid  = threadIdx.x;
    const int bm   = blockIdx.x * 64;
    const int tm   = (tid >> 4) * 4;
    const int tn   = (tid & 15) * 4;
    const int lrow = tid >> 2;
    const int lk   = (tid & 3) * 4;

    float acc[4][4];
#pragma unroll
    for (int i = 0; i < 4; ++i)
#pragma unroll
        for (int j = 0; j < 4; ++j) acc[i][j] = 0.f;

    for (int k0 = 0; k0 < K; k0 += 16) {
        const int kk = k0 + lk;
        float4 av = *(const float4*)(A + (size_t)(bm + lrow) * K + kk);
        float4 wv = *(const float4*)(W + (size_t)lrow * K + kk);   // N=64 rows
        __syncthreads();
        As[lk + 0][lrow] = av.x; As[lk + 1][lrow] = av.y;
        As[lk + 2][lrow] = av.z; As[lk + 3][lrow] = av.w;
        Ws[lk + 0][lrow] = wv.x; Ws[lk + 1][lrow] = wv.y;
        Ws[lk + 2][lrow] = wv.z; Ws[lk + 3][lrow] = wv.w;
        __syncthreads();
#pragma unroll
        for (int k = 0; k < 16; ++k) {
            float4 a4 = *(const float4*)&As[k][tm];
            float4 b4 = *(const float4*)&Ws[k][tn];
            float a[4] = {a4.x, a4.y, a4.z, a4.w};
            float b[4] = {b4.x, b4.y, b4.z, b4.w};
#pragma unroll
            for (int i = 0; i < 4; ++i)
#pragma unroll
                for (int j = 0; j < 4; ++j)
                    acc[i][j] = fmaf(a[i], b[j], acc[i][j]);
        }
    }
#pragma unroll
    for (int i = 0; i < 4; ++i)
        *(float4*)(C + (size_t)(bm + tm + i) * N + tn) =
            make_float4(acc[i][0], acc[i][1], acc[i][2], acc[i][3]);
}

// ---------------- causal depthwise conv (k=4) + SiLU ----------------
__global__ __launch_bounds__(256) void conv_silu_k(
    const float* __restrict__ xz, const float* __restrict__ cw,
    const float* __restrict__ cb, float* __restrict__ xc)
{
    const int idx = blockIdx.x * 256 + threadIdx.x;   // bl*DINNER + e
    const int e  = idx & (DINNER - 1);
    const int bl = idx >> 10;
    const int l  = bl & (L_SZ - 1);
    const float4 w = *(const float4*)(cw + e * 4);
    const size_t rs = 2 * DINNER;
    float acc = cb[e];
    acc = fmaf(xz[(size_t)bl * rs + e], w.w, acc);
    if (l >= 1) acc = fmaf(xz[(size_t)(bl - 1) * rs + e], w.z, acc);
    if (l >= 2) acc = fmaf(xz[(size_t)(bl - 2) * rs + e], w.y, acc);
    if (l >= 3) acc = fmaf(xz[(size_t)(bl - 3) * rs + e], w.x, acc);
    xc[idx] = acc / (1.f + expf(-acc));
}

// ---------------- dt = softplus(dbc[:, :32] @ dt_proj_w^T + b) ----------------
// DTROWS rows per block: weight float4s held in registers and reused across rows ->
// Wdt L2 traffic drops from BL*128KB (512MB) to (BL/DTROWS)*128KB (32MB).
__global__ __launch_bounds__(256) void dt_softplus_k(
    const float* __restrict__ dbc, const float* __restrict__ Wdt,
    const float* __restrict__ bdt, float* __restrict__ dt)
{
    __shared__ float r[DTROWS][DTRANK];
    const int rb  = blockIdx.x * DTROWS;
    const int tid = threadIdx.x;
    for (int i = tid; i < DTROWS * DTRANK; i += 256)
        r[i >> 5][i & 31] = dbc[(size_t)(rb + (i >> 5)) * 64 + (i & 31)];
    __syncthreads();
    for (int n = tid; n < DINNER; n += 256) {
        float4 wv[8];
        const float* w = Wdt + (size_t)n * DTRANK;
#pragma unroll
        for (int q = 0; q < 8; ++q) wv[q] = *(const float4*)(w + q * 4);
        const float bn_ = bdt[n];
#pragma unroll
        for (int row = 0; row < DTROWS; ++row) {
            float acc = bn_;
#pragma unroll
            for (int q = 0; q < 8; ++q) {
                acc = fmaf(wv[q].x, r[row][q * 4 + 0], acc);
                acc = fmaf(wv[q].y, r[row][q * 4 + 1], acc);
                acc = fmaf(wv[q].z, r[row][q * 4 + 2], acc);
                acc = fmaf(wv[q].w, r[row][q * 4 + 3], acc);
            }
            dt[(size_t)(rb + row) * DINNER + n] = (acc > 20.f) ? acc : log1pf(expf(acc));
        }
    }
}

// ---------------- selective scan; epilogue fuses +xc*D and *silu(z) ----------------
// 128 threads = 8 e-channels x 16 states; PF-deep register-ring prefetch (static idx).
// Only 0.5 waves/SIMD here -> the ring is the only latency hiding; PF=8 gives a
// ~280-cycle load->use lead vs ~300-500cy L3/HBM latency.
// y aliases dtb: ring reads row l+PF before y row l+PF is written (PF iters later,
// same wave program order); each wave touches only its own e-columns -> no hazard.
__global__ __launch_bounds__(128) void scan_k(
    const float* dtb, const float* __restrict__ xc,
    const float* __restrict__ xz, const float* __restrict__ dbc,
    const float* __restrict__ A_log, const float* __restrict__ Dp,
    float* y)
{
    const int b   = blockIdx.x >> 7;
    const int eg  = blockIdx.x & 127;
    const int tid = threadIdx.x;
    const int el  = tid >> 4;
    const int s   = tid & 15;
    const int e   = eg * 8 + el;

    const float Av = -expf(A_log[e * DSTATE + s]);
    const float Dv = Dp[e];
    float h = 0.f;
    const size_t base = (size_t)b * L_SZ;

    float dtv[PF], xcv[PF], Bv[PF], Cv[PF], zv[PF];
#pragma unroll
    for (int p = 0; p < PF; ++p) {
        const size_t bl = base + p;
        dtv[p] = dtb[bl * DINNER + e];
        xcv[p] = xc [bl * DINNER + e];
        Bv[p]  = dbc[bl * 64 + DTRANK + s];
        Cv[p]  = dbc[bl * 64 + DTRANK + DSTATE + s];
        zv[p]  = xz [bl * (2 * DINNER) + DINNER + e];
    }

    for (int l0 = 0; l0 < L_SZ; l0 += PF) {
#pragma unroll
        for (int p = 0; p < PF; ++p) {
            const int l = l0 + p;
            h = fmaf(expf(dtv[p] * Av), h, dtv[p] * Bv[p] * xcv[p]);
            float yp = h * Cv[p];
            yp += __shfl_xor(yp, 1, 16);
            yp += __shfl_xor(yp, 2, 16);
            yp += __shfl_xor(yp, 4, 16);
            yp += __shfl_xor(yp, 8, 16);
            if (s == 0) {
                const float sg = zv[p] / (1.f + expf(-zv[p]));
                y[(base + l) * DINNER + e] = fmaf(xcv[p], Dv, yp) * sg;
            }
            const int ln = l + PF;
            if (ln < L_SZ) {
                const size_t bl = base + ln;
                dtv[p] = dtb[bl * DINNER + e];
                xcv[p] = xc [bl * DINNER + e];
                Bv[p]  = dbc[bl * 64 + DTRANK + s];
                Cv[p]  = dbc[bl * 64 + DTRANK + DSTATE + s];
                zv[p]  = xz [bl * (2 * DINNER) + DINNER + e];
            }
        }
    }
}

extern "C" void kernel_launch(void* const* d_in, const int* in_sizes, int n_in,
                              void* d_out, int out_size, void* d_ws, size_t ws_size,
                              hipStream_t stream)
{
    const float* x         = (const float*)d_in[0];
    const float* context   = (const float*)d_in[1];
    const float* in_proj_w = (const float*)d_in[2];
    const float* conv_w    = (const float*)d_in[3];
    const float* conv_b    = (const float*)d_in[4];
    const float* x_proj_w  = (const float*)d_in[5];
    const float* dt_proj_w = (const float*)d_in[6];
    const float* dt_proj_b = (const float*)d_in[7];
    const float* A_log     = (const float*)d_in[8];
    const float* Dvec      = (const float*)d_in[9];
    const float* out_proj_w= (const float*)d_in[10];
    const float* gate_w    = (const float*)d_in[11];
    const float* gate_b    = (const float*)d_in[12];
    float* out = (float*)d_out;

    // ---- workspace layout (byte offsets; peak 81MB) ----
    // Lifetime overlays: x_hi/x_lo live only through GEMM-1 -> share the m region
    // (m written at step 6). y_hi/y_lo/A7_* live only after scan -> share dead xz.
    char* wsb = (char*)d_ws;
    float* xz   = (float*)(wsb + (size_t)( 0u << 20));  // 32MB [xi | z]
    float* xc   = (float*)(wsb + (size_t)(32u << 20));  // 16MB
    float* dbc  = (float*)(wsb + (size_t)(48u << 20));  //  1MB
    float* dt   = (float*)(wsb + (size_t)(49u << 20));  // 16MB (y aliases)
    float* m    = (float*)(wsb + (size_t)(65u << 20));  //  8MB (written step 6)
    u16* x_hi   = (u16*)(wsb + (size_t)(65u << 20));    //  4MB (overlay on m, dead after step 1)
    u16* x_lo   = (u16*)(wsb + (size_t)(69u << 20));    //  4MB (overlay on m)
    u16* Wi_hi  = (u16*)(wsb + (size_t)(73u << 20));    //  2MB
    u16* Wi_lo  = (u16*)(wsb + (size_t)(75u << 20));    //  2MB
    u16* Wo_hi  = (u16*)(wsb + (size_t)(77u << 20));    //  1MB
    u16* Wo_lo  = (u16*)(wsb + (size_t)(78u << 20));    //  1MB
    u16* Wg_hi  = (u16*)(wsb + (size_t)(79u << 20));    //  1MB
    u16* Wg_lo  = (u16*)(wsb + (size_t)(80u << 20));    //  1MB -> 81MB total
    // overlays inside dead xz region (valid only after scan_k):
    u16* y_hi   = (u16*)(wsb + (size_t)( 0u << 20));    //  8MB
    u16* y_lo   = (u16*)(wsb + (size_t)( 8u << 20));    //  8MB
    u16* A7_hi  = (u16*)(wsb + (size_t)(16u << 20));    //  8MB [bf16(m) | bf16(context)]
    u16* A7_lo  = (u16*)(wsb + (size_t)(24u << 20));    //  8MB
    float* y    = dt;

    // 0. hi/lo splits of x and the three big weights
    cvt_hl_k<<<1024, 256, 0, stream>>>(x,          x_hi,  x_lo,   9,  512, 0);
    cvt_hl_k<<< 512, 256, 0, stream>>>(in_proj_w,  Wi_hi, Wi_lo,  9,  512, 0);
    cvt_hl_k<<< 256, 256, 0, stream>>>(out_proj_w, Wo_hi, Wo_lo, 10, 1024, 0);
    cvt_hl_k<<< 256, 256, 0, stream>>>(gate_w,     Wg_hi, Wg_lo, 10, 1024, 0);
    // 1. xz = x @ in_proj_w^T                       [4096, 2048]
    gemm_bf16hl<4, 0><<<dim3(BL / 128, 2048 / 128), 256, 0, stream>>>(
        x_hi, x_lo, Wi_hi, Wi_lo, nullptr, nullptr, xz, BL, 2048, DMODEL);
    // 2. xc = silu(causal_conv(xi))                 [4096, 1024]
    conv_silu_k<<<(BL * DINNER) / 256, 256, 0, stream>>>(xz, conv_w, conv_b, xc);
    // 3. dbc = xc @ x_proj_w^T                      [4096, 64]
    gemm_xproj<<<dim3(BL / 64, 1), 256, 0, stream>>>(xc, x_proj_w, dbc, BL, 64, DINNER);
    // 4. dt = softplus(dbc[:,:32] @ dt_proj_w^T + b) [4096, 1024]
    dt_softplus_k<<<BL / DTROWS, 256, 0, stream>>>(dbc, dt_proj_w, dt_proj_b, dt);
    // 5. selective scan + fused skip/gate epilogue -> y (aliases dt; last read of xz)
    scan_k<<<B_SZ * 128, 128, 0, stream>>>(dt, xc, xz, dbc, A_log, Dvec, y);
    // 6. m = y @ out_proj_w^T                       [4096, 512]
    cvt_hl_k<<<2048, 256, 0, stream>>>(y, y_hi, y_lo, 10, 1024, 0);
    gemm_bf16hl<2, 0><<<dim3(BL / 128, DMODEL / 64), 256, 0, stream>>>(
        y_hi, y_lo, Wo_hi, Wo_lo, nullptr, nullptr, m, BL, DMODEL, DINNER);
    // 7. out = m * sigmoid([m | context] @ gate_w^T + gate_b)   [4096, 512]
    cvt_hl_k<<<1024, 256, 0, stream>>>(m,       A7_hi, A7_lo, 9, 1024, 0);
    cvt_hl_k<<<1024, 256, 0, stream>>>(context, A7_hi, A7_lo, 9, 1024, DMODEL);
    gemm_bf16hl<2, 1><<<dim3(BL / 128, DMODEL / 64), 256, 0, stream>>>(
        A7_hi, A7_lo, Wg_hi, Wg_lo, gate_b, m, out, BL, DMODEL, 2 * DMODEL);
}

// Round 11
// 484.628 us; speedup vs baseline: 2.4861x; 2.4861x over previous
//
#include <hip/hip_runtime.h>
#include <cstdint>
#include <cstddef>

#define B_SZ   2
#define L_SZ   2048
#define BL     (B_SZ * L_SZ)   // 4096
#define DMODEL 512
#define DINNER 1024
#define DSTATE 16
#define DTRANK 32
#define DTROWS 16              // rows per block in dt_softplus_k (Wdt reuse factor)
#define NCH    16              // scan chunks (parallel)
#define CHL    (L_SZ / NCH)    // 128 steps per chunk

typedef unsigned short u16;
typedef __attribute__((ext_vector_type(8))) short          bf16x8;  // 8 bf16 in 4 VGPRs (guide §3)
typedef __attribute__((ext_vector_type(8))) unsigned short u16x8;
typedef __attribute__((ext_vector_type(4))) float          f32x4;

// async global->LDS, 16B per lane, linear dest (wave-uniform base + lane*16)
__device__ __forceinline__ void gload16(const void* g, void* l) {
    __builtin_amdgcn_global_load_lds(
        (const __attribute__((address_space(1))) unsigned int*)g,
        (__attribute__((address_space(3))) unsigned int*)l, 16, 0, 0);
}

__device__ __forceinline__ u16 bf16_rne(float x) {
    unsigned u = __float_as_uint(x);
    return (u16)((u + 0x7fffu + ((u >> 16) & 1u)) >> 16);
}

// ---------------- fp32 -> bf16 hi/lo split (hi = rne(x), lo = rne(x - hi)) ----------------
__global__ __launch_bounds__(256) void cvt_hl_k(
    const float* __restrict__ src, u16* __restrict__ hi, u16* __restrict__ lo,
    int shift, int dst_stride, int col_off)
{
    const long long base = ((long long)blockIdx.x * 256 + threadIdx.x) * 8;
    const long long row  = base >> shift;
    const int       col  = (int)(base & ((1 << shift) - 1));
    float4 f0 = *(const float4*)(src + base);
    float4 f1 = *(const float4*)(src + base + 4);
    float f[8] = {f0.x, f0.y, f0.z, f0.w, f1.x, f1.y, f1.z, f1.w};
    u16x8 h8, l8;
#pragma unroll
    for (int i = 0; i < 8; ++i) {
        u16 hb = bf16_rne(f[i]);
        float hf = __uint_as_float((unsigned)hb << 16);
        h8[i] = hb;
        l8[i] = bf16_rne(f[i] - hf);
    }
    const long long d = row * dst_stride + col_off + col;
    *(u16x8*)(hi + d) = h8;
    *(u16x8*)(lo + d) = l8;
}

// ---------------- MFMA GEMM: C[M,N] = (Ah+Al)[M,K] @ (Wh+Wl)[N,K]^T (lo*lo dropped) ----
// m97 structure: BM=128, BN=NF*32, BK=32, 4 waves, single-buffered 2-barrier loop.
// EPI: 0 = plain f32 store; 1 = C[o] = Mul[o] * sigmoid(acc + bias[col]);
//      2 = split store: col < DINNER -> C (xi), else -> C2 (z), both stride DINNER.
template<int NF, int EPI>
__global__ __launch_bounds__(256) void gemm_bf16hl(
    const u16* __restrict__ Ah, const u16* __restrict__ Al,
    const u16* __restrict__ Wh, const u16* __restrict__ Wl,
    const float* __restrict__ bias, const float* __restrict__ Mul,
    float* __restrict__ C, float* __restrict__ C2, int M, int N, int K)
{
    constexpr int BN  = NF * 32;
    constexpr int NIB = BN / 16;
    constexpr int TOT = 16 + 2 * NIB;
    __shared__ u16 sAh[128][32], sAl[128][32];
    __shared__ u16 sBh[BN][32],  sBl[BN][32];

    const int tid  = threadIdx.x;
    const int w    = tid >> 6;
    const int lane = tid & 63;
    const int bm   = blockIdx.x * 128;
    const int bn   = blockIdx.y * BN;
    const int wm   = w >> 1;
    const int wn   = w & 1;
    const int lm   = lane & 15;
    const int lk8  = (lane >> 4) * 8;
    const int srow = lane >> 2;
    const int scol = (lane & 3) * 8;

    f32x4 acc[4][NF];
#pragma unroll
    for (int i = 0; i < 4; ++i)
#pragma unroll
        for (int j = 0; j < NF; ++j) acc[i][j] = (f32x4){0.f, 0.f, 0.f, 0.f};

    for (int k0 = 0; k0 < K; k0 += 32) {
        __syncthreads();
        for (int idx = w; idx < TOT; idx += 4) {
            const u16* gs; u16* ls;
            if (idx < 8)            { gs = Ah + (size_t)(bm + idx * 16 + srow) * K;              ls = &sAh[idx * 16][0]; }
            else if (idx < 16)      { gs = Al + (size_t)(bm + (idx - 8) * 16 + srow) * K;        ls = &sAl[(idx - 8) * 16][0]; }
            else if (idx < 16 + NIB){ gs = Wh + (size_t)(bn + (idx - 16) * 16 + srow) * K;       ls = &sBh[(idx - 16) * 16][0]; }
            else                    { gs = Wl + (size_t)(bn + (idx - 16 - NIB) * 16 + srow) * K; ls = &sBl[(idx - 16 - NIB) * 16][0]; }
            gload16(gs + k0 + scol, ls);
        }
        __syncthreads();

        bf16x8 a_h[4], a_l[4], b_h[NF], b_l[NF];
#pragma unroll
        for (int mi = 0; mi < 4; ++mi) {
            a_h[mi] = *(const bf16x8*)&sAh[wm * 64 + mi * 16 + lm][lk8];
            a_l[mi] = *(const bf16x8*)&sAl[wm * 64 + mi * 16 + lm][lk8];
        }
#pragma unroll
        for (int ni = 0; ni < NF; ++ni) {
            b_h[ni] = *(const bf16x8*)&sBh[wn * (NF * 16) + ni * 16 + lm][lk8];
            b_l[ni] = *(const bf16x8*)&sBl[wn * (NF * 16) + ni * 16 + lm][lk8];
        }
#pragma unroll
        for (int mi = 0; mi < 4; ++mi)
#pragma unroll
            for (int ni = 0; ni < NF; ++ni) {
                acc[mi][ni] = __builtin_amdgcn_mfma_f32_16x16x32_bf16(a_h[mi], b_h[ni], acc[mi][ni], 0, 0, 0);
                acc[mi][ni] = __builtin_amdgcn_mfma_f32_16x16x32_bf16(a_h[mi], b_l[ni], acc[mi][ni], 0, 0, 0);
                acc[mi][ni] = __builtin_amdgcn_mfma_f32_16x16x32_bf16(a_l[mi], b_h[ni], acc[mi][ni], 0, 0, 0);
            }
    }

    const int lr4 = (lane >> 4) * 4;
#pragma unroll
    for (int mi = 0; mi < 4; ++mi)
#pragma unroll
        for (int ni = 0; ni < NF; ++ni)
#pragma unroll
            for (int r = 0; r < 4; ++r) {
                const int row = bm + wm * 64 + mi * 16 + lr4 + r;
                const int col = bn + wn * (NF * 16) + ni * 16 + lm;
                if (EPI == 0) {
                    C[(size_t)row * N + col] = acc[mi][ni][r];
                } else if (EPI == 1) {
                    const size_t o = (size_t)row * N + col;
                    const float v = acc[mi][ni][r] + bias[col];
                    C[o] = Mul[o] / (1.f + expf(-v));
                } else {                                    // EPI == 2: split xi | z
                    if (col < DINNER) C [(size_t)row * DINNER + col]          = acc[mi][ni][r];
                    else              C2[(size_t)row * DINNER + col - DINNER] = acc[mi][ni][r];
                }
            }
}

// ---------------- small vector GEMM for x_proj (N=64): C = A @ W^T ----------------
__global__ __launch_bounds__(256) void gemm_xproj(
    const float* __restrict__ A, const float* __restrict__ W,
    float* __restrict__ C, int M, int N, int K)
{
    __shared__ float As[16][64];
    __shared__ float Ws[16][64];
    const int tid  = threadIdx.x;
    const int bm   = blockIdx.x * 64;
    const int tm   = (tid >> 4) * 4;
    const int tn   = (tid & 15) * 4;
    const int lrow = tid >> 2;
    const int lk   = (tid & 3) * 4;

    float acc[4][4];
#pragma unroll
    for (int i = 0; i < 4; ++i)
#pragma unroll
        for (int j = 0; j < 4; ++j) acc[i][j] = 0.f;

    for (int k0 = 0; k0 < K; k0 += 16) {
        const int kk = k0 + lk;
        float4 av = *(const float4*)(A + (size_t)(bm + lrow) * K + kk);
        float4 wv = *(const float4*)(W + (size_t)lrow * K + kk);
        __syncthreads();
        As[lk + 0][lrow] = av.x; As[lk + 1][lrow] = av.y;
        As[lk + 2][lrow] = av.z; As[lk + 3][lrow] = av.w;
        Ws[lk + 0][lrow] = wv.x; Ws[lk + 1][lrow] = wv.y;
        Ws[lk + 2][lrow] = wv.z; Ws[lk + 3][lrow] = wv.w;
        __syncthreads();
#pragma unroll
        for (int k = 0; k < 16; ++k) {
            float4 a4 = *(const float4*)&As[k][tm];
            float4 b4 = *(const float4*)&Ws[k][tn];
            float a[4] = {a4.x, a4.y, a4.z, a4.w};
            float b[4] = {b4.x, b4.y, b4.z, b4.w};
#pragma unroll
            for (int i = 0; i < 4; ++i)
#pragma unroll
                for (int j = 0; j < 4; ++j)
                    acc[i][j] = fmaf(a[i], b[j], acc[i][j]);
        }
    }
#pragma unroll
    for (int i = 0; i < 4; ++i)
        *(float4*)(C + (size_t)(bm + tm + i) * N + tn) =
            make_float4(acc[i][0], acc[i][1], acc[i][2], acc[i][3]);
}

// ---------------- causal depthwise conv (k=4) + SiLU; input xi stride DINNER ----------
__global__ __launch_bounds__(256) void conv_silu_k(
    const float* __restrict__ xi, const float* __restrict__ cw,
    const float* __restrict__ cb, float* __restrict__ xc)
{
    const int idx = blockIdx.x * 256 + threadIdx.x;
    const int e  = idx & (DINNER - 1);
    const int bl = idx >> 10;
    const int l  = bl & (L_SZ - 1);
    const float4 w = *(const float4*)(cw + e * 4);
    float acc = cb[e];
    acc = fmaf(xi[(size_t)bl * DINNER + e], w.w, acc);
    if (l >= 1) acc = fmaf(xi[(size_t)(bl - 1) * DINNER + e], w.z, acc);
    if (l >= 2) acc = fmaf(xi[(size_t)(bl - 2) * DINNER + e], w.y, acc);
    if (l >= 3) acc = fmaf(xi[(size_t)(bl - 3) * DINNER + e], w.x, acc);
    xc[idx] = acc / (1.f + expf(-acc));
}

// ---------------- dt = softplus(dbc[:, :32] @ dt_proj_w^T + b), DTROWS rows/block ----
__global__ __launch_bounds__(256) void dt_softplus_k(
    const float* __restrict__ dbc, const float* __restrict__ Wdt,
    const float* __restrict__ bdt, float* __restrict__ dt)
{
    __shared__ float r[DTROWS][DTRANK];
    const int rb  = blockIdx.x * DTROWS;
    const int tid = threadIdx.x;
    for (int i = tid; i < DTROWS * DTRANK; i += 256)
        r[i >> 5][i & 31] = dbc[(size_t)(rb + (i >> 5)) * 64 + (i & 31)];
    __syncthreads();
    for (int n = tid; n < DINNER; n += 256) {
        float4 wv[8];
        const float* w = Wdt + (size_t)n * DTRANK;
#pragma unroll
        for (int q = 0; q < 8; ++q) wv[q] = *(const float4*)(w + q * 4);
        const float bn_ = bdt[n];
#pragma unroll
        for (int row = 0; row < DTROWS; ++row) {
            float acc = bn_;
#pragma unroll
            for (int q = 0; q < 8; ++q) {
                acc = fmaf(wv[q].x, r[row][q * 4 + 0], acc);
                acc = fmaf(wv[q].y, r[row][q * 4 + 1], acc);
                acc = fmaf(wv[q].z, r[row][q * 4 + 2], acc);
                acc = fmaf(wv[q].w, r[row][q * 4 + 3], acc);
            }
            dt[(size_t)(rb + row) * DINNER + n] = (acc > 20.f) ? acc : log1pf(expf(acc));
        }
    }
}

// ================= chunked selective scan: 16x parallelism over L =================
// Independent scalar linear recurrence per (b,e,s). Block = (b, eg, c): 128 thr = 8e x 16s.
// grid 4096 blocks -> ~8 waves/SIMD (was 0.5): TLP hides load latency. No y/dt alias.

// Pass 1: local chunk state H_c (h0=0) and decay product P_c = prod(exp(dt*A)).
__global__ __launch_bounds__(128) void scan_p1(
    const float* __restrict__ dtb, const float* __restrict__ xc,
    const float* __restrict__ dbc, const float* __restrict__ A_log,
    float* __restrict__ Pst, float* __restrict__ Hst)
{
    const int bid = blockIdx.x;
    const int c  = bid & (NCH - 1);
    const int eg = (bid >> 4) & 127;
    const int b  = bid >> 11;
    const int tid = threadIdx.x;
    const int el = tid >> 4, s = tid & 15;
    const int e  = eg * 8 + el;

    const float Av = -expf(A_log[e * DSTATE + s]);
    const size_t base = (size_t)b * L_SZ + c * CHL;
    float h = 0.f, P = 1.f;

    float dtv = dtb[base * DINNER + e];
    float xcv = xc [base * DINNER + e];
    float Bv  = dbc[base * 64 + DTRANK + s];
    for (int l = 0; l < CHL; ++l) {
        float dt_n = 0.f, xc_n = 0.f, B_n = 0.f;
        if (l + 1 < CHL) {
            const size_t r = base + l + 1;
            dt_n = dtb[r * DINNER + e];
            xc_n = xc [r * DINNER + e];
            B_n  = dbc[r * 64 + DTRANK + s];
        }
        const float dA = expf(dtv * Av);
        h = fmaf(dA, h, dtv * Bv * xcv);
        P *= dA;
        dtv = dt_n; xcv = xc_n; Bv = B_n;
    }
    const size_t off = (((size_t)c * B_SZ + b) * DINNER + e) * DSTATE + s;
    Pst[off] = P;
    Hst[off] = h;
}

// Combine: 16-step sequential prefix per (b,e,s); Hst[c] becomes the INCOMING state h_in(c).
__global__ __launch_bounds__(256) void scan_comb(
    const float* __restrict__ Pst, float* __restrict__ Hst)
{
    const int idx = blockIdx.x * 256 + threadIdx.x;   // [0, B*DINNER*DSTATE)
    float h = 0.f;
    for (int c = 0; c < NCH; ++c) {
        const size_t off = (size_t)c * (B_SZ * DINNER * DSTATE) + idx;
        const float P = Pst[off];
        const float H = Hst[off];
        Hst[off] = h;               // incoming state for chunk c
        h = fmaf(P, h, H);          // h_end(c) = H_c + P_c * h_in(c)
    }
}

// Pass 2: re-run chunk from h_in; fuse +xc*D and *silu(z); emit y as bf16 hi/lo.
__global__ __launch_bounds__(128) void scan_p2(
    const float* __restrict__ dtb, const float* __restrict__ xc,
    const float* __restrict__ z, const float* __restrict__ dbc,
    const float* __restrict__ A_log, const float* __restrict__ Dp,
    const float* __restrict__ H0,
    u16* __restrict__ y_hi, u16* __restrict__ y_lo)
{
    const int bid = blockIdx.x;
    const int c  = bid & (NCH - 1);
    const int eg = (bid >> 4) & 127;
    const int b  = bid >> 11;
    const int tid = threadIdx.x;
    const int el = tid >> 4, s = tid & 15;
    const int e  = eg * 8 + el;

    const float Av = -expf(A_log[e * DSTATE + s]);
    const float Dv = Dp[e];
    const size_t base = (size_t)b * L_SZ + c * CHL;
    float h = H0[(((size_t)c * B_SZ + b) * DINNER + e) * DSTATE + s];

    float dtv = dtb[base * DINNER + e];
    float xcv = xc [base * DINNER + e];
    float Bv  = dbc[base * 64 + DTRANK + s];
    float Cv  = dbc[base * 64 + DTRANK + DSTATE + s];
    float zv  = z  [base * DINNER + e];
    for (int l = 0; l < CHL; ++l) {
        float dt_n = 0.f, xc_n = 0.f, B_n = 0.f, C_n = 0.f, z_n = 0.f;
        if (l + 1 < CHL) {
            const size_t r = base + l + 1;
            dt_n = dtb[r * DINNER + e];
            xc_n = xc [r * DINNER + e];
            B_n  = dbc[r * 64 + DTRANK + s];
            C_n  = dbc[r * 64 + DTRANK + DSTATE + s];
            z_n  = z  [r * DINNER + e];
        }
        h = fmaf(expf(dtv * Av), h, dtv * Bv * xcv);
        float yp = h * Cv;
        yp += __shfl_xor(yp, 1, 16);
        yp += __shfl_xor(yp, 2, 16);
        yp += __shfl_xor(yp, 4, 16);
        yp += __shfl_xor(yp, 8, 16);
        if (s == 0) {
            const float sg = zv / (1.f + expf(-zv));
            const float yv = fmaf(xcv, Dv, yp) * sg;
            const u16 hb = bf16_rne(yv);
            const float hf = __uint_as_float((unsigned)hb << 16);
            const size_t o = (base + l) * DINNER + e;
            y_hi[o] = hb;
            y_lo[o] = bf16_rne(yv - hf);
        }
        dtv = dt_n; xcv = xc_n; Bv = B_n; Cv = C_n; zv = z_n;
    }
}

extern "C" void kernel_launch(void* const* d_in, const int* in_sizes, int n_in,
                              void* d_out, int out_size, void* d_ws, size_t ws_size,
                              hipStream_t stream)
{
    const float* x         = (const float*)d_in[0];
    const float* context   = (const float*)d_in[1];
    const float* in_proj_w = (const float*)d_in[2];
    const float* conv_w    = (const float*)d_in[3];
    const float* conv_b    = (const float*)d_in[4];
    const float* x_proj_w  = (const float*)d_in[5];
    const float* dt_proj_w = (const float*)d_in[6];
    const float* dt_proj_b = (const float*)d_in[7];
    const float* A_log     = (const float*)d_in[8];
    const float* Dvec      = (const float*)d_in[9];
    const float* out_proj_w= (const float*)d_in[10];
    const float* gate_w    = (const float*)d_in[11];
    const float* gate_b    = (const float*)d_in[12];
    float* out = (float*)d_out;

    // ---- workspace layout (byte offsets; peak 81MB == confirmed-safe budget) ----
    // GEMM-1 splits output into xi|z. Overlays: y_hi/y_lo on xi (dead after conv);
    // A7_* on z (dead after scan_p2); x_hi/x_lo on m (written step 6); Pst/Hst on
    // Wi_hi/Wi_lo (dead after GEMM-1).
    char* wsb = (char*)d_ws;
    float* xi   = (float*)(wsb + (size_t)( 0u << 20));  // 16MB
    float* z    = (float*)(wsb + (size_t)(16u << 20));  // 16MB
    float* xc   = (float*)(wsb + (size_t)(32u << 20));  // 16MB
    float* dbc  = (float*)(wsb + (size_t)(48u << 20));  //  1MB
    float* dt   = (float*)(wsb + (size_t)(49u << 20));  // 16MB
    float* m    = (float*)(wsb + (size_t)(65u << 20));  //  8MB (written step 6)
    u16* x_hi   = (u16*)(wsb + (size_t)(65u << 20));    //  4MB overlay on m
    u16* x_lo   = (u16*)(wsb + (size_t)(69u << 20));    //  4MB overlay on m
    u16* Wi_hi  = (u16*)(wsb + (size_t)(73u << 20));    //  2MB (dead after GEMM-1)
    u16* Wi_lo  = (u16*)(wsb + (size_t)(75u << 20));    //  2MB (dead after GEMM-1)
    float* Pst  = (float*)(wsb + (size_t)(73u << 20));  //  2MB overlay
    float* Hst  = (float*)(wsb + (size_t)(75u << 20));  //  2MB overlay
    u16* Wo_hi  = (u16*)(wsb + (size_t)(77u << 20));    //  1MB
    u16* Wo_lo  = (u16*)(wsb + (size_t)(78u << 20));    //  1MB
    u16* Wg_hi  = (u16*)(wsb + (size_t)(79u << 20));    //  1MB
    u16* Wg_lo  = (u16*)(wsb + (size_t)(80u << 20));    //  1MB -> 81MB peak
    u16* y_hi   = (u16*)(wsb + (size_t)( 0u << 20));    //  8MB overlay on dead xi
    u16* y_lo   = (u16*)(wsb + (size_t)( 8u << 20));    //  8MB overlay on dead xi
    u16* A7_hi  = (u16*)(wsb + (size_t)(16u << 20));    //  8MB overlay on dead z
    u16* A7_lo  = (u16*)(wsb + (size_t)(24u << 20));    //  8MB overlay on dead z

    // 0. hi/lo splits of x and the three big weights
    cvt_hl_k<<<1024, 256, 0, stream>>>(x,          x_hi,  x_lo,   9,  512, 0);
    cvt_hl_k<<< 512, 256, 0, stream>>>(in_proj_w,  Wi_hi, Wi_lo,  9,  512, 0);
    cvt_hl_k<<< 256, 256, 0, stream>>>(out_proj_w, Wo_hi, Wo_lo, 10, 1024, 0);
    cvt_hl_k<<< 256, 256, 0, stream>>>(gate_w,     Wg_hi, Wg_lo, 10, 1024, 0);
    // 1. [xi | z] = x @ in_proj_w^T  (split epilogue)     [4096, 2048]
    gemm_bf16hl<4, 2><<<dim3(BL / 128, 2048 / 128), 256, 0, stream>>>(
        x_hi, x_lo, Wi_hi, Wi_lo, nullptr, nullptr, xi, z, BL, 2048, DMODEL);
    // 2. xc = silu(causal_conv(xi))                       [4096, 1024]
    conv_silu_k<<<(BL * DINNER) / 256, 256, 0, stream>>>(xi, conv_w, conv_b, xc);
    // 3. dbc = xc @ x_proj_w^T                            [4096, 64]
    gemm_xproj<<<dim3(BL / 64, 1), 256, 0, stream>>>(xc, x_proj_w, dbc, BL, 64, DINNER);
    // 4. dt = softplus(dbc[:,:32] @ dt_proj_w^T + b)      [4096, 1024]
    dt_softplus_k<<<BL / DTROWS, 256, 0, stream>>>(dbc, dt_proj_w, dt_proj_b, dt);
    // 5. chunked selective scan (16x L-parallel) -> y_hi/y_lo (bf16, fused gate)
    scan_p1<<<B_SZ * 128 * NCH, 128, 0, stream>>>(dt, xc, dbc, A_log, Pst, Hst);
    scan_comb<<<(B_SZ * DINNER * DSTATE) / 256, 256, 0, stream>>>(Pst, Hst);
    scan_p2<<<B_SZ * 128 * NCH, 128, 0, stream>>>(dt, xc, z, dbc, A_log, Dvec, Hst,
                                                  y_hi, y_lo);
    // 6. m = y @ out_proj_w^T                             [4096, 512]
    gemm_bf16hl<2, 0><<<dim3(BL / 128, DMODEL / 64), 256, 0, stream>>>(
        y_hi, y_lo, Wo_hi, Wo_lo, nullptr, nullptr, m, nullptr, BL, DMODEL, DINNER);
    // 7. out = m * sigmoid([m | context] @ gate_w^T + gate_b)   [4096, 512]
    cvt_hl_k<<<1024, 256, 0, stream>>>(m,       A7_hi, A7_lo, 9, 1024, 0);
    cvt_hl_k<<<1024, 256, 0, stream>>>(context, A7_hi, A7_lo, 9, 1024, DMODEL);
    gemm_bf16hl<2, 1><<<dim3(BL / 128, DMODEL / 64), 256, 0, stream>>>(
        A7_hi, A7_lo, Wg_hi, Wg_lo, gate_b, m, out, nullptr, BL, DMODEL, 2 * DMODEL);
}

// Round 12
// 405.551 us; speedup vs baseline: 2.9709x; 1.1950x over previous
//
#include <hip/hip_runtime.h>
#include <cstdint>
#include <cstddef>

#define B_SZ   2
#define L_SZ   2048
#define BL     (B_SZ * L_SZ)   // 4096
#define DMODEL 512
#define DINNER 1024
#define DSTATE 16
#define DTRANK 32
#define DTROWS 16              // rows per block in dt_softplus_k (Wdt reuse factor)
#define NCH    32              // scan chunks (parallel)
#define CHL    (L_SZ / NCH)    // 64 steps per chunk

typedef unsigned short u16;
typedef __attribute__((ext_vector_type(8))) short          bf16x8;  // 8 bf16 in 4 VGPRs (guide §3)
typedef __attribute__((ext_vector_type(8))) unsigned short u16x8;
typedef __attribute__((ext_vector_type(4))) float          f32x4;

// async global->LDS, 16B per lane, linear dest (wave-uniform base + lane*16)
__device__ __forceinline__ void gload16(const void* g, void* l) {
    __builtin_amdgcn_global_load_lds(
        (const __attribute__((address_space(1))) unsigned int*)g,
        (__attribute__((address_space(3))) unsigned int*)l, 16, 0, 0);
}

__device__ __forceinline__ u16 bf16_rne(float x) {
    unsigned u = __float_as_uint(x);
    return (u16)((u + 0x7fffu + ((u >> 16) & 1u)) >> 16);
}

// ---------------- fp32 -> bf16 hi/lo split (hi = rne(x), lo = rne(x - hi)) ----------------
__global__ __launch_bounds__(256) void cvt_hl_k(
    const float* __restrict__ src, u16* __restrict__ hi, u16* __restrict__ lo,
    int shift, int dst_stride, int col_off)
{
    const long long base = ((long long)blockIdx.x * 256 + threadIdx.x) * 8;
    const long long row  = base >> shift;
    const int       col  = (int)(base & ((1 << shift) - 1));
    float4 f0 = *(const float4*)(src + base);
    float4 f1 = *(const float4*)(src + base + 4);
    float f[8] = {f0.x, f0.y, f0.z, f0.w, f1.x, f1.y, f1.z, f1.w};
    u16x8 h8, l8;
#pragma unroll
    for (int i = 0; i < 8; ++i) {
        u16 hb = bf16_rne(f[i]);
        float hf = __uint_as_float((unsigned)hb << 16);
        h8[i] = hb;
        l8[i] = bf16_rne(f[i] - hf);
    }
    const long long d = row * dst_stride + col_off + col;
    *(u16x8*)(hi + d) = h8;
    *(u16x8*)(lo + d) = l8;
}

// ---------------- MFMA GEMM: C[M,N] = (Ah+Al)[M,K] @ (Wh+Wl)[N,K]^T (lo*lo dropped) ----
// m97 structure: BM=128, BN=NF*32, BK=32, 4 waves, single-buffered 2-barrier loop.
// EPI: 0 = plain f32 store; 1 = C[o] = Mul[o] * sigmoid(acc + bias[col]);
//      2 = split store: col < DINNER -> C (xi), else -> C2 (z), both stride DINNER.
template<int NF, int EPI>
__global__ __launch_bounds__(256) void gemm_bf16hl(
    const u16* __restrict__ Ah, const u16* __restrict__ Al,
    const u16* __restrict__ Wh, const u16* __restrict__ Wl,
    const float* __restrict__ bias, const float* __restrict__ Mul,
    float* __restrict__ C, float* __restrict__ C2, int M, int N, int K)
{
    constexpr int BN  = NF * 32;
    constexpr int NIB = BN / 16;
    constexpr int TOT = 16 + 2 * NIB;
    __shared__ u16 sAh[128][32], sAl[128][32];
    __shared__ u16 sBh[BN][32],  sBl[BN][32];

    const int tid  = threadIdx.x;
    const int w    = tid >> 6;
    const int lane = tid & 63;
    const int bm   = blockIdx.x * 128;
    const int bn   = blockIdx.y * BN;
    const int wm   = w >> 1;
    const int wn   = w & 1;
    const int lm   = lane & 15;
    const int lk8  = (lane >> 4) * 8;
    const int srow = lane >> 2;
    const int scol = (lane & 3) * 8;

    f32x4 acc[4][NF];
#pragma unroll
    for (int i = 0; i < 4; ++i)
#pragma unroll
        for (int j = 0; j < NF; ++j) acc[i][j] = (f32x4){0.f, 0.f, 0.f, 0.f};

    for (int k0 = 0; k0 < K; k0 += 32) {
        __syncthreads();
        for (int idx = w; idx < TOT; idx += 4) {
            const u16* gs; u16* ls;
            if (idx < 8)            { gs = Ah + (size_t)(bm + idx * 16 + srow) * K;              ls = &sAh[idx * 16][0]; }
            else if (idx < 16)      { gs = Al + (size_t)(bm + (idx - 8) * 16 + srow) * K;        ls = &sAl[(idx - 8) * 16][0]; }
            else if (idx < 16 + NIB){ gs = Wh + (size_t)(bn + (idx - 16) * 16 + srow) * K;       ls = &sBh[(idx - 16) * 16][0]; }
            else                    { gs = Wl + (size_t)(bn + (idx - 16 - NIB) * 16 + srow) * K; ls = &sBl[(idx - 16 - NIB) * 16][0]; }
            gload16(gs + k0 + scol, ls);
        }
        __syncthreads();

        bf16x8 a_h[4], a_l[4], b_h[NF], b_l[NF];
#pragma unroll
        for (int mi = 0; mi < 4; ++mi) {
            a_h[mi] = *(const bf16x8*)&sAh[wm * 64 + mi * 16 + lm][lk8];
            a_l[mi] = *(const bf16x8*)&sAl[wm * 64 + mi * 16 + lm][lk8];
        }
#pragma unroll
        for (int ni = 0; ni < NF; ++ni) {
            b_h[ni] = *(const bf16x8*)&sBh[wn * (NF * 16) + ni * 16 + lm][lk8];
            b_l[ni] = *(const bf16x8*)&sBl[wn * (NF * 16) + ni * 16 + lm][lk8];
        }
#pragma unroll
        for (int mi = 0; mi < 4; ++mi)
#pragma unroll
            for (int ni = 0; ni < NF; ++ni) {
                acc[mi][ni] = __builtin_amdgcn_mfma_f32_16x16x32_bf16(a_h[mi], b_h[ni], acc[mi][ni], 0, 0, 0);
                acc[mi][ni] = __builtin_amdgcn_mfma_f32_16x16x32_bf16(a_h[mi], b_l[ni], acc[mi][ni], 0, 0, 0);
                acc[mi][ni] = __builtin_amdgcn_mfma_f32_16x16x32_bf16(a_l[mi], b_h[ni], acc[mi][ni], 0, 0, 0);
            }
    }

    const int lr4 = (lane >> 4) * 4;
#pragma unroll
    for (int mi = 0; mi < 4; ++mi)
#pragma unroll
        for (int ni = 0; ni < NF; ++ni)
#pragma unroll
            for (int r = 0; r < 4; ++r) {
                const int row = bm + wm * 64 + mi * 16 + lr4 + r;
                const int col = bn + wn * (NF * 16) + ni * 16 + lm;
                if (EPI == 0) {
                    C[(size_t)row * N + col] = acc[mi][ni][r];
                } else if (EPI == 1) {
                    const size_t o = (size_t)row * N + col;
                    const float v = acc[mi][ni][r] + bias[col];
                    C[o] = Mul[o] / (1.f + expf(-v));
                } else {                                    // EPI == 2: split xi | z
                    if (col < DINNER) C [(size_t)row * DINNER + col]          = acc[mi][ni][r];
                    else              C2[(size_t)row * DINNER + col - DINNER] = acc[mi][ni][r];
                }
            }
}

// ---------------- small vector GEMM for x_proj (N=64): C = A @ W^T ----------------
__global__ __launch_bounds__(256) void gemm_xproj(
    const float* __restrict__ A, const float* __restrict__ W,
    float* __restrict__ C, int M, int N, int K)
{
    __shared__ float As[16][64];
    __shared__ float Ws[16][64];
    const int tid  = threadIdx.x;
    const int bm   = blockIdx.x * 64;
    const int tm   = (tid >> 4) * 4;
    const int tn   = (tid & 15) * 4;
    const int lrow = tid >> 2;
    const int lk   = (tid & 3) * 4;

    float acc[4][4];
#pragma unroll
    for (int i = 0; i < 4; ++i)
#pragma unroll
        for (int j = 0; j < 4; ++j) acc[i][j] = 0.f;

    for (int k0 = 0; k0 < K; k0 += 16) {
        const int kk = k0 + lk;
        float4 av = *(const float4*)(A + (size_t)(bm + lrow) * K + kk);
        float4 wv = *(const float4*)(W + (size_t)lrow * K + kk);
        __syncthreads();
        As[lk + 0][lrow] = av.x; As[lk + 1][lrow] = av.y;
        As[lk + 2][lrow] = av.z; As[lk + 3][lrow] = av.w;
        Ws[lk + 0][lrow] = wv.x; Ws[lk + 1][lrow] = wv.y;
        Ws[lk + 2][lrow] = wv.z; Ws[lk + 3][lrow] = wv.w;
        __syncthreads();
#pragma unroll
        for (int k = 0; k < 16; ++k) {
            float4 a4 = *(const float4*)&As[k][tm];
            float4 b4 = *(const float4*)&Ws[k][tn];
            float a[4] = {a4.x, a4.y, a4.z, a4.w};
            float b[4] = {b4.x, b4.y, b4.z, b4.w};
#pragma unroll
            for (int i = 0; i < 4; ++i)
#pragma unroll
                for (int j = 0; j < 4; ++j)
                    acc[i][j] = fmaf(a[i], b[j], acc[i][j]);
        }
    }
#pragma unroll
    for (int i = 0; i < 4; ++i)
        *(float4*)(C + (size_t)(bm + tm + i) * N + tn) =
            make_float4(acc[i][0], acc[i][1], acc[i][2], acc[i][3]);
}

// ---------------- causal depthwise conv (k=4) + SiLU; input xi stride DINNER ----------
__global__ __launch_bounds__(256) void conv_silu_k(
    const float* __restrict__ xi, const float* __restrict__ cw,
    const float* __restrict__ cb, float* __restrict__ xc)
{
    const int idx = blockIdx.x * 256 + threadIdx.x;
    const int e  = idx & (DINNER - 1);
    const int bl = idx >> 10;
    const int l  = bl & (L_SZ - 1);
    const float4 w = *(const float4*)(cw + e * 4);
    float acc = cb[e];
    acc = fmaf(xi[(size_t)bl * DINNER + e], w.w, acc);
    if (l >= 1) acc = fmaf(xi[(size_t)(bl - 1) * DINNER + e], w.z, acc);
    if (l >= 2) acc = fmaf(xi[(size_t)(bl - 2) * DINNER + e], w.y, acc);
    if (l >= 3) acc = fmaf(xi[(size_t)(bl - 3) * DINNER + e], w.x, acc);
    xc[idx] = acc / (1.f + expf(-acc));
}

// ---------------- dt = softplus(dbc[:, :32] @ dt_proj_w^T + b), DTROWS rows/block ----
__global__ __launch_bounds__(256) void dt_softplus_k(
    const float* __restrict__ dbc, const float* __restrict__ Wdt,
    const float* __restrict__ bdt, float* __restrict__ dt)
{
    __shared__ float r[DTROWS][DTRANK];
    const int rb  = blockIdx.x * DTROWS;
    const int tid = threadIdx.x;
    for (int i = tid; i < DTROWS * DTRANK; i += 256)
        r[i >> 5][i & 31] = dbc[(size_t)(rb + (i >> 5)) * 64 + (i & 31)];
    __syncthreads();
    for (int n = tid; n < DINNER; n += 256) {
        float4 wv[8];
        const float* w = Wdt + (size_t)n * DTRANK;
#pragma unroll
        for (int q = 0; q < 8; ++q) wv[q] = *(const float4*)(w + q * 4);
        const float bn_ = bdt[n];
#pragma unroll
        for (int row = 0; row < DTROWS; ++row) {
            float acc = bn_;
#pragma unroll
            for (int q = 0; q < 8; ++q) {
                acc = fmaf(wv[q].x, r[row][q * 4 + 0], acc);
                acc = fmaf(wv[q].y, r[row][q * 4 + 1], acc);
                acc = fmaf(wv[q].z, r[row][q * 4 + 2], acc);
                acc = fmaf(wv[q].w, r[row][q * 4 + 3], acc);
            }
            dt[(size_t)(rb + row) * DINNER + n] = (acc > 20.f) ? acc : log1pf(expf(acc));
        }
    }
}

// ============ chunked scan, thread = (e, 8-state half): registers not shuffles ============
// Block = 256 thr covers 128 e x 2 halves; grid = B x 8 e-groups x NCH chunks = 512.
// Per step: 3 coalesced loads (dt/xc/z) + row-local B/C float4s; 8 exp2 + ~24 fma.
// A2 = A*log2e precomputed -> native v_exp_f32; p1 decay folds to exp2(A2 * sum(dt)).

__global__ __launch_bounds__(256) void scan_p1(
    const float* __restrict__ dtb, const float* __restrict__ xc,
    const float* __restrict__ dbc, const float* __restrict__ A_log,
    float* __restrict__ Pst, float* __restrict__ Hst)
{
    const int bid = blockIdx.x;
    const int c   = bid & (NCH - 1);
    const int eg  = (bid >> 5) & 7;
    const int b   = bid >> 8;
    const int tid = threadIdx.x;
    const int e    = eg * 128 + (tid >> 1);
    const int s0   = (tid & 1) * 8;

    float A2[8];
    {
        float4 a0 = *(const float4*)(A_log + e * DSTATE + s0);
        float4 a1 = *(const float4*)(A_log + e * DSTATE + s0 + 4);
        const float c2 = 1.44269504088896f;
        A2[0] = -expf(a0.x) * c2; A2[1] = -expf(a0.y) * c2;
        A2[2] = -expf(a0.z) * c2; A2[3] = -expf(a0.w) * c2;
        A2[4] = -expf(a1.x) * c2; A2[5] = -expf(a1.y) * c2;
        A2[6] = -expf(a1.z) * c2; A2[7] = -expf(a1.w) * c2;
    }
    float h[8] = {0.f, 0.f, 0.f, 0.f, 0.f, 0.f, 0.f, 0.f};
    float dtsum = 0.f;
    const size_t base = (size_t)b * L_SZ + (size_t)c * CHL;
    const float* dtp = dtb + base * DINNER + e;
    const float* xcp = xc  + base * DINNER + e;
    const float* dbp = dbc + base * 64 + DTRANK + s0;   // B half
    float dtv = *dtp, xcv = *xcp;

    for (int l = 0; l < CHL; ++l) {
        float4 B0 = *(const float4*)(dbp);
        float4 B1 = *(const float4*)(dbp + 4);
        const size_t adv = (l + 1 < CHL) ? DINNER : 0;
        float dt_n = dtp[adv];
        float xc_n = xcp[adv];
        dtsum += dtv;
        const float u = dtv * xcv;
        const float Bs[8] = {B0.x, B0.y, B0.z, B0.w, B1.x, B1.y, B1.z, B1.w};
#pragma unroll
        for (int j = 0; j < 8; ++j) {
            const float dA = exp2f(dtv * A2[j]);
            h[j] = fmaf(dA, h[j], Bs[j] * u);
        }
        dtv = dt_n; xcv = xc_n;
        dtp += DINNER; xcp += DINNER; dbp += 64;
    }
    const size_t off = (((size_t)c * B_SZ + b) * DINNER + e) * DSTATE + s0;
    *(float4*)(Pst + off)     = make_float4(exp2f(A2[0] * dtsum), exp2f(A2[1] * dtsum),
                                            exp2f(A2[2] * dtsum), exp2f(A2[3] * dtsum));
    *(float4*)(Pst + off + 4) = make_float4(exp2f(A2[4] * dtsum), exp2f(A2[5] * dtsum),
                                            exp2f(A2[6] * dtsum), exp2f(A2[7] * dtsum));
    *(float4*)(Hst + off)     = make_float4(h[0], h[1], h[2], h[3]);
    *(float4*)(Hst + off + 4) = make_float4(h[4], h[5], h[6], h[7]);
}

// Combine: NCH-step sequential prefix per (b,e,s); Hst[c] becomes the INCOMING state.
__global__ __launch_bounds__(256) void scan_comb(
    const float* __restrict__ Pst, float* __restrict__ Hst)
{
    const int idx = blockIdx.x * 256 + threadIdx.x;   // [0, B*DINNER*DSTATE)
    float h = 0.f;
    for (int c = 0; c < NCH; ++c) {
        const size_t off = (size_t)c * (B_SZ * DINNER * DSTATE) + idx;
        const float P = Pst[off];
        const float H = Hst[off];
        Hst[off] = h;               // incoming state for chunk c
        h = fmaf(P, h, H);          // h_end(c) = H_c + P_c * h_in(c)
    }
}

// Pass 2: re-run chunk from h_in; pair-shfl reduce; fuse +xc*D and *silu(z); bf16 hi/lo y.
__global__ __launch_bounds__(256) void scan_p2(
    const float* __restrict__ dtb, const float* __restrict__ xc,
    const float* __restrict__ z, const float* __restrict__ dbc,
    const float* __restrict__ A_log, const float* __restrict__ Dp,
    const float* __restrict__ H0,
    u16* __restrict__ y_hi, u16* __restrict__ y_lo)
{
    const int bid = blockIdx.x;
    const int c   = bid & (NCH - 1);
    const int eg  = (bid >> 5) & 7;
    const int b   = bid >> 8;
    const int tid = threadIdx.x;
    const int e    = eg * 128 + (tid >> 1);
    const int half = tid & 1;
    const int s0   = half * 8;

    float A2[8];
    {
        float4 a0 = *(const float4*)(A_log + e * DSTATE + s0);
        float4 a1 = *(const float4*)(A_log + e * DSTATE + s0 + 4);
        const float c2 = 1.44269504088896f;
        A2[0] = -expf(a0.x) * c2; A2[1] = -expf(a0.y) * c2;
        A2[2] = -expf(a0.z) * c2; A2[3] = -expf(a0.w) * c2;
        A2[4] = -expf(a1.x) * c2; A2[5] = -expf(a1.y) * c2;
        A2[6] = -expf(a1.z) * c2; A2[7] = -expf(a1.w) * c2;
    }
    const float Dv = Dp[e];
    const size_t base = (size_t)b * L_SZ + (size_t)c * CHL;
    const size_t hoff = (((size_t)c * B_SZ + b) * DINNER + e) * DSTATE + s0;
    float h[8];
    {
        float4 h0 = *(const float4*)(H0 + hoff);
        float4 h1 = *(const float4*)(H0 + hoff + 4);
        h[0] = h0.x; h[1] = h0.y; h[2] = h0.z; h[3] = h0.w;
        h[4] = h1.x; h[5] = h1.y; h[6] = h1.z; h[7] = h1.w;
    }
    const float* dtp = dtb + base * DINNER + e;
    const float* xcp = xc  + base * DINNER + e;
    const float* zp  = z   + base * DINNER + e;
    const float* dbp = dbc + base * 64 + DTRANK + s0;
    float dtv = *dtp, xcv = *xcp, zv = *zp;

    for (int l = 0; l < CHL; ++l) {
        float4 B0 = *(const float4*)(dbp);
        float4 B1 = *(const float4*)(dbp + 4);
        float4 C0 = *(const float4*)(dbp + DSTATE);
        float4 C1 = *(const float4*)(dbp + DSTATE + 4);
        const size_t adv = (l + 1 < CHL) ? DINNER : 0;
        float dt_n = dtp[adv];
        float xc_n = xcp[adv];
        float z_n  = zp[adv];
        const float u = dtv * xcv;
        const float Bs[8] = {B0.x, B0.y, B0.z, B0.w, B1.x, B1.y, B1.z, B1.w};
        const float Cs[8] = {C0.x, C0.y, C0.z, C0.w, C1.x, C1.y, C1.z, C1.w};
        float yp = 0.f;
#pragma unroll
        for (int j = 0; j < 8; ++j) {
            const float dA = exp2f(dtv * A2[j]);
            h[j] = fmaf(dA, h[j], Bs[j] * u);
            yp = fmaf(h[j], Cs[j], yp);
        }
        yp += __shfl_xor(yp, 1);                    // pair partner: other 8 states
        const float sg = zv / (1.f + expf(-zv));
        const float yv = fmaf(xcv, Dv, yp) * sg;
        const u16 hb = bf16_rne(yv);
        const size_t o = (base + l) * DINNER + e;
        if (half == 0) y_hi[o] = hb;
        else           y_lo[o] = bf16_rne(yv - __uint_as_float((unsigned)hb << 16));
        dtv = dt_n; xcv = xc_n; zv = z_n;
        dtp += DINNER; xcp += DINNER; zp += DINNER; dbp += 64;
    }
}

extern "C" void kernel_launch(void* const* d_in, const int* in_sizes, int n_in,
                              void* d_out, int out_size, void* d_ws, size_t ws_size,
                              hipStream_t stream)
{
    const float* x         = (const float*)d_in[0];
    const float* context   = (const float*)d_in[1];
    const float* in_proj_w = (const float*)d_in[2];
    const float* conv_w    = (const float*)d_in[3];
    const float* conv_b    = (const float*)d_in[4];
    const float* x_proj_w  = (const float*)d_in[5];
    const float* dt_proj_w = (const float*)d_in[6];
    const float* dt_proj_b = (const float*)d_in[7];
    const float* A_log     = (const float*)d_in[8];
    const float* Dvec      = (const float*)d_in[9];
    const float* out_proj_w= (const float*)d_in[10];
    const float* gate_w    = (const float*)d_in[11];
    const float* gate_b    = (const float*)d_in[12];
    float* out = (float*)d_out;

    // ---- workspace layout (byte offsets; peak 81MB == confirmed-safe budget) ----
    // Time-shared m region @65-73MB: [steps 0-1] x_hi/x_lo -> [step 5] Pst/Hst ->
    // [steps 6-7] m. y_hi/y_lo overlay xi (dead after conv); A7_* overlay z (dead
    // after scan_p2).
    char* wsb = (char*)d_ws;
    float* xi   = (float*)(wsb + (size_t)( 0u << 20));  // 16MB
    float* z    = (float*)(wsb + (size_t)(16u << 20));  // 16MB
    float* xc   = (float*)(wsb + (size_t)(32u << 20));  // 16MB
    float* dbc  = (float*)(wsb + (size_t)(48u << 20));  //  1MB
    float* dt   = (float*)(wsb + (size_t)(49u << 20));  // 16MB
    float* m    = (float*)(wsb + (size_t)(65u << 20));  //  8MB (written step 6)
    u16* x_hi   = (u16*)(wsb + (size_t)(65u << 20));    //  4MB overlay on m
    u16* x_lo   = (u16*)(wsb + (size_t)(69u << 20));    //  4MB overlay on m
    float* Pst  = (float*)(wsb + (size_t)(65u << 20));  //  4MB overlay on m (step 5)
    float* Hst  = (float*)(wsb + (size_t)(69u << 20));  //  4MB overlay on m (step 5)
    u16* Wi_hi  = (u16*)(wsb + (size_t)(73u << 20));    //  2MB
    u16* Wi_lo  = (u16*)(wsb + (size_t)(75u << 20));    //  2MB
    u16* Wo_hi  = (u16*)(wsb + (size_t)(77u << 20));    //  1MB
    u16* Wo_lo  = (u16*)(wsb + (size_t)(78u << 20));    //  1MB
    u16* Wg_hi  = (u16*)(wsb + (size_t)(79u << 20));    //  1MB
    u16* Wg_lo  = (u16*)(wsb + (size_t)(80u << 20));    //  1MB -> 81MB peak
    u16* y_hi   = (u16*)(wsb + (size_t)( 0u << 20));    //  8MB overlay on dead xi
    u16* y_lo   = (u16*)(wsb + (size_t)( 8u << 20));    //  8MB overlay on dead xi
    u16* A7_hi  = (u16*)(wsb + (size_t)(16u << 20));    //  8MB overlay on dead z
    u16* A7_lo  = (u16*)(wsb + (size_t)(24u << 20));    //  8MB overlay on dead z

    // 0. hi/lo splits of x and the three big weights
    cvt_hl_k<<<1024, 256, 0, stream>>>(x,          x_hi,  x_lo,   9,  512, 0);
    cvt_hl_k<<< 512, 256, 0, stream>>>(in_proj_w,  Wi_hi, Wi_lo,  9,  512, 0);
    cvt_hl_k<<< 256, 256, 0, stream>>>(out_proj_w, Wo_hi, Wo_lo, 10, 1024, 0);
    cvt_hl_k<<< 256, 256, 0, stream>>>(gate_w,     Wg_hi, Wg_lo, 10, 1024, 0);
    // 1. [xi | z] = x @ in_proj_w^T  (split epilogue)     [4096, 2048]
    gemm_bf16hl<4, 2><<<dim3(BL / 128, 2048 / 128), 256, 0, stream>>>(
        x_hi, x_lo, Wi_hi, Wi_lo, nullptr, nullptr, xi, z, BL, 2048, DMODEL);
    // 2. xc = silu(causal_conv(xi))                       [4096, 1024]
    conv_silu_k<<<(BL * DINNER) / 256, 256, 0, stream>>>(xi, conv_w, conv_b, xc);
    // 3. dbc = xc @ x_proj_w^T                            [4096, 64]
    gemm_xproj<<<dim3(BL / 64, 1), 256, 0, stream>>>(xc, x_proj_w, dbc, BL, 64, DINNER);
    // 4. dt = softplus(dbc[:,:32] @ dt_proj_w^T + b)      [4096, 1024]
    dt_softplus_k<<<BL / DTROWS, 256, 0, stream>>>(dbc, dt_proj_w, dt_proj_b, dt);
    // 5. chunked selective scan (32x L-parallel, 8 states/thread) -> y_hi/y_lo
    scan_p1<<<B_SZ * 8 * NCH, 256, 0, stream>>>(dt, xc, dbc, A_log, Pst, Hst);
    scan_comb<<<(B_SZ * DINNER * DSTATE) / 256, 256, 0, stream>>>(Pst, Hst);
    scan_p2<<<B_SZ * 8 * NCH, 256, 0, stream>>>(dt, xc, z, dbc, A_log, Dvec, Hst,
                                                y_hi, y_lo);
    // 6. m = y @ out_proj_w^T                             [4096, 512]
    gemm_bf16hl<2, 0><<<dim3(BL / 128, DMODEL / 64), 256, 0, stream>>>(
        y_hi, y_lo, Wo_hi, Wo_lo, nullptr, nullptr, m, nullptr, BL, DMODEL, DINNER);
    // 7. out = m * sigmoid([m | context] @ gate_w^T + gate_b)   [4096, 512]
    cvt_hl_k<<<1024, 256, 0, stream>>>(m,       A7_hi, A7_lo, 9, 1024, 0);
    cvt_hl_k<<<1024, 256, 0, stream>>>(context, A7_hi, A7_lo, 9, 1024, DMODEL);
    gemm_bf16hl<2, 1><<<dim3(BL / 128, DMODEL / 64), 256, 0, stream>>>(
        A7_hi, A7_lo, Wg_hi, Wg_lo, gate_b, m, out, nullptr, BL, DMODEL, 2 * DMODEL);
}